// Round 13
// baseline (424.691 us; speedup 1.0000x reference)
//
#include <hip/hip_runtime.h>

// GCN + low-rank global attention (LRGA), N=100k, E=1.6M, D=128, K=64.
// R1: k_out -> bf16 MFMA with folded Weff.
// R2: k_gemm1 -> split-bf16 (hi/lo) MFMA 3-pass.
// R3: k_red -> atomic-free two-stage MFMA reduction.
// R4: FAILED (fused split in k-loop / weight hoist). R5: reg dbuf = null.
// R6: scatter XCD-shard = null. R7: fragment-order gemm1 layouts. WIN.
// R8: HW lesson: sparse 8B stores cost a full HBM line; only dense stores avoid it.
// R9: scatter -> LDS counting sort + dense flush. WIN.
// R10: k_red/k_out coalescing = ~null. R11: k_deg fold + aggn/out fuse. WIN.
// R12: k_red dbuf pipeline; k_d/k_fixup folds. WIN (-9us).
// R13: k_split + k_gemm1 fused into k_gemm1f: 64-row tile, 6 waves (one per 64-col
//      tile), x staged coalesced + split ONCE into 32KB LDS fragment buffer; deletes
//      the 153MB xhF/xloF round-trip. (R4's failure was per-colblk 3x re-conversion
//      + VGPR collapse, not conversion cost: 141M VALU ops ~ 3us chip-wide.)
#define DIN   128
#define DOUT  128
#define KR    64
#define TCOLS 256   // 4*K
#define WCOLS 384   // DOUT + TCOLS
#define P_RED 512   // stage-1 partial blocks
#define PSTR  4224  // 4096 VtZ + 128 colsum
#define STCAP 6144  // pass-B LDS staging (edges per 256-node quarter, 1.5x mean)

typedef unsigned short ushort_t;
typedef __attribute__((ext_vector_type(8))) short bf16x8;
typedef __attribute__((ext_vector_type(4))) float f32x4;

__device__ __forceinline__ float bf2f(unsigned short u) {
  return __uint_as_float(((unsigned int)u) << 16);
}
__device__ __forceinline__ unsigned short f2bf(float f) {
  unsigned int b = __float_as_uint(f);
  b = b + 0x7FFFu + ((b >> 16) & 1u);
  return (unsigned short)(b >> 16);
}

// ---------------------------------------------------------------- init
__global__ __launch_bounds__(256) void k_init(int* __restrict__ degc, float* __restrict__ VtZ,
                                              float* __restrict__ colsum, int* __restrict__ bcur,
                                              int* __restrict__ ocnt, int N) {
  int i = blockIdx.x * 256 + threadIdx.x;
  if (i < N) degc[i] = 1;            // self-loop gives deg >= 1
  if (i < 4096) VtZ[i] = 0.f;
  if (i < 128) colsum[i] = 0.f;
  if (i < 128) bcur[i] = 0;
  if (i == 0) ocnt[0] = 0;
}

// ---------------------------------------------------------------- weights -> bf16 hi/lo, FRAGMENT ORDER.
__global__ __launch_bounds__(256) void k_wprep(const float* __restrict__ Wg, const float* __restrict__ Wa,
                                               ushort_t* __restrict__ whF, ushort_t* __restrict__ wlF) {
  int g = blockIdx.x * 256 + threadIdx.x;
  int f = g >> 6, l = g & 63;
  int c16 = f >> 2, s = f & 3;
  int col = c16 * 16 + (l & 15);
  int k = s * 32 + ((l >> 4) << 3);
#pragma unroll
  for (int j = 0; j < 8; ++j) {
    float v = (col < DOUT) ? Wg[(size_t)(k + j) * DOUT + col]
                           : Wa[(size_t)(k + j) * TCOLS + (col - DOUT)];
    ushort_t h = f2bf(v);
    whF[(size_t)g * 8 + j] = h;
    wlF[(size_t)g * 8 + j] = f2bf(v - bf2f(h));
  }
}

// ---------------------------------------------------------------- hierarchical scan, stage 1
__global__ __launch_bounds__(256) void k_scan1(const int* __restrict__ degc, int* __restrict__ offs,
                                               int* __restrict__ bsums, int N) {
  __shared__ int s[256];
  int tid = threadIdx.x;
  int base = blockIdx.x * 1024 + tid * 4;
  int c[4], e[4];
#pragma unroll
  for (int q = 0; q < 4; ++q) c[q] = (base + q < N) ? (degc[base + q] - 1) : 0;
  e[0] = 0; e[1] = c[0]; e[2] = e[1] + c[1]; e[3] = e[2] + c[2];
  int tsum = e[3] + c[3];
  s[tid] = tsum; __syncthreads();
  for (int off = 1; off < 256; off <<= 1) {
    int v = (tid >= off) ? s[tid - off] : 0;
    __syncthreads();
    s[tid] += v;
    __syncthreads();
  }
  int tb = s[tid] - tsum;
#pragma unroll
  for (int q = 0; q < 4; ++q) if (base + q < N) offs[base + q] = tb + e[q];
  if (tid == 255) bsums[blockIdx.x] = s[255];
}

// stage 2: exclusive scan of block sums (NBLK <= 128)
__global__ __launch_bounds__(128) void k_scan2(const int* __restrict__ bsums, int* __restrict__ boff,
                                               int* __restrict__ offs, int NBLK, int N) {
  __shared__ int s[128];
  int tid = threadIdx.x;
  int v = (tid < NBLK) ? bsums[tid] : 0;
  s[tid] = v; __syncthreads();
  for (int off = 1; off < 128; off <<= 1) {
    int u = (tid >= off) ? s[tid - off] : 0;
    __syncthreads();
    s[tid] += u;
    __syncthreads();
  }
  boff[tid] = s[tid] - v;
  if (tid == 127) offs[N] = s[127];   // total = E
}

// stage 3: add block offsets; dinv = rsqrt(deg)
__global__ __launch_bounds__(256) void k_scan3(int* __restrict__ offs, const int* __restrict__ boff,
                                               const int* __restrict__ degc, float* __restrict__ dinv,
                                               int N) {
  int i = blockIdx.x * 256 + threadIdx.x;
  if (i < N) {
    offs[i] += boff[i >> 10];
    dinv[i] = rsqrtf((float)degc[i]);
  }
}

// ---------------------------------------------------------------- pass A: bin edges by dst range (1024-node bins).
// Also accumulates degc (k_deg folded in).
__global__ __launch_bounds__(256) void k_bin(const int* __restrict__ ei, int* __restrict__ bcur,
                                             int* __restrict__ degc,
                                             int2* __restrict__ buckets,
                                             int2* __restrict__ oflow, int* __restrict__ ocnt,
                                             int E, int B, int CAP) {
  __shared__ int hist[128], pref[128], place[128], gbase[128];
  __shared__ int2 st[4096];
  int tid = threadIdx.x;
  int e0 = blockIdx.x * 4096;
  int nE = min(4096, E - e0);
  if (nE <= 0) return;

  if (tid < 128) { hist[tid] = 0; place[tid] = 0; }
  __syncthreads();

  int src[16], dst[16];
#pragma unroll
  for (int q = 0; q < 16; ++q) {
    int idx = tid + q * 256;
    if (idx < nE) {
      src[q] = ei[e0 + idx];
      dst[q] = ei[E + e0 + idx];
      atomicAdd(&hist[dst[q] >> 10], 1);
      atomicAdd(&degc[dst[q]], 1);          // folded k_deg
    }
  }
  __syncthreads();

  if (tid < 128) pref[tid] = hist[tid];
  __syncthreads();
  for (int off = 1; off < 128; off <<= 1) {
    int v = (tid < 128 && tid >= off) ? pref[tid - off] : 0;
    __syncthreads();
    if (tid < 128) pref[tid] += v;
    __syncthreads();
  }
  if (tid < 128) pref[tid] -= hist[tid];
  if (tid < B && hist[tid] > 0) gbase[tid] = atomicAdd(&bcur[tid], hist[tid]);
  __syncthreads();

#pragma unroll
  for (int q = 0; q < 16; ++q) {
    int idx = tid + q * 256;
    if (idx < nE) {
      int b = dst[q] >> 10;
      int p = pref[b] + atomicAdd(&place[b], 1);
      st[p] = make_int2(src[q], dst[q]);
    }
  }
  __syncthreads();

  for (int i = tid; i < nE; i += 256) {
    int2 q = st[i];
    int b = q.y >> 10;
    int gp = gbase[b] + (i - pref[b]);
    if (gp < CAP) {
      buckets[(size_t)b * CAP + gp] = q;
    } else {
      int oi = atomicAdd(ocnt, 1);
      oflow[oi] = q;
    }
  }
}

// ---------------------------------------------------------------- pass B: LDS counting sort, dense flush.
// Pass-A overflow handled in-block after the flush (k_fixup folded in).
__global__ __launch_bounds__(256) void k_scatter2(const int2* __restrict__ buckets,
                                                  const int* __restrict__ bcur,
                                                  const int* __restrict__ offs,
                                                  const float* __restrict__ dinv,
                                                  const int2* __restrict__ oflow,
                                                  const int* __restrict__ ocnt,
                                                  int2* __restrict__ csr, int CAP, int N) {
  __shared__ int lcur[256];
  __shared__ int2 st[STCAP];
  int cb = blockIdx.x >> 2;
  int lo = cb * 1024 + (blockIdx.x & 3) * 256;
  if (lo >= N) return;
  int tid = threadIdx.x;
  int nnode = min(256, N - lo);
  int base = offs[lo];
  int nb = offs[lo + nnode] - base;     // true edge count for this quarter
  if (tid < nnode) lcur[tid] = offs[lo + tid];   // absolute positions
  __syncthreads();
  int avail = min(bcur[cb], CAP);
  const int2* sp = &buckets[(size_t)cb * CAP];
  bool staged = (nb <= STCAP);
  int quarter = lo >> 8;
  for (int i = tid; i < avail; i += 256) {
    int2 q = sp[i];
    if ((q.y >> 8) != quarter) continue;
    int p = atomicAdd(&lcur[q.y - lo], 1);
    int2 c;
    c.x = q.x;
    c.y = __float_as_int(dinv[q.x] * dinv[q.y]);
    if (staged) st[p - base] = c;
    else        csr[p] = c;
  }
  __syncthreads();
  if (staged) {
    for (int i = tid; i < nb; i += 256) csr[base + i] = st[i];  // DENSE flush
  }
  __syncthreads();
  // folded fixup: drain pass-A overflow edges belonging to this quarter
  int n = ocnt[0];
  for (int i = tid; i < n; i += 256) {
    int2 q = oflow[i];
    if ((q.y >> 8) != quarter) continue;
    int p = atomicAdd(&lcur[q.y - lo], 1);
    int2 c;
    c.x = q.x;
    c.y = __float_as_int(dinv[q.x] * dinv[q.y]);
    csr[p] = c;
  }
}

// ---------------------------------------------------------------- FUSED split + GEMM (R13).
// Block = 64-row tile, 384 threads = 6 waves, wave w owns cols w*64..w*64+63 of the
// 384 output cols. x staged coalesced, hi/lo split ONCE into LDS fragment layout;
// inner loop identical math to R7 (3-pass split bf16 MFMA).
__global__ __launch_bounds__(384) void k_gemm1f(const float* __restrict__ x,
                                                const ushort_t* __restrict__ whF,
                                                const ushort_t* __restrict__ wlF,
                                                const float* __restrict__ ba,
                                                ushort_t* __restrict__ hs, ushort_t* __restrict__ t,
                                                int N) {
  __shared__ ushort_t ahs[16 * 512];   // 16 fragments (4 r16-groups x 4 ksteps), hi
  __shared__ ushort_t als[16 * 512];   // lo
  int tid = threadIdx.x;
  int lane = tid & 63;
  int w = tid >> 6;            // 0..5 -> col tile
  int r0 = blockIdx.x * 64;

  // stage + split: 64 rows x 128 cols fp32 -> LDS fragment layout, converted once.
  for (int idx = tid; idx < 2048; idx += 384) {
    int r = idx >> 5;          // 0..63
    int k = (idx & 31) * 4;    // 0..124 step 4
    int row = r0 + r;
    float4 v = (row < N) ? *(const float4*)&x[(size_t)row * DIN + k]
                         : make_float4(0.f, 0.f, 0.f, 0.f);
    ushort4 h, l;
    h.x = f2bf(v.x); h.y = f2bf(v.y); h.z = f2bf(v.z); h.w = f2bf(v.w);
    l.x = f2bf(v.x - bf2f(h.x)); l.y = f2bf(v.y - bf2f(h.y));
    l.z = f2bf(v.z - bf2f(h.z)); l.w = f2bf(v.w - bf2f(h.w));
    int frag = (r >> 4) * 4 + (k >> 5);
    int slot = (r & 15) + (((k & 31) >> 3) << 4);
    int off = frag * 512 + slot * 8 + (k & 7);
    *(ushort4*)&ahs[off] = h;
    *(ushort4*)&als[off] = l;
  }
  __syncthreads();

  int lr = lane & 15;
  int rq = (lane >> 4) * 4;
  int c16b = w * 4;            // B col-group base (16-col units)
  f32x4 acc[4][4] = {};

#pragma unroll
  for (int s = 0; s < 4; ++s) {
    bf16x8 ahf[4], alf[4], bhf[4], blf[4];
#pragma unroll
    for (int m = 0; m < 4; ++m) {
      ahf[m] = *(const bf16x8*)&ahs[(m * 4 + s) * 512 + lane * 8];
      alf[m] = *(const bf16x8*)&als[(m * 4 + s) * 512 + lane * 8];
    }
#pragma unroll
    for (int n = 0; n < 4; ++n) {
      size_t fo = (((size_t)(c16b + n) * 4 + s) * 64 + lane) * 8;
      bhf[n] = *(const bf16x8*)&whF[fo];
      blf[n] = *(const bf16x8*)&wlF[fo];
    }
#pragma unroll
    for (int m = 0; m < 4; ++m)
#pragma unroll
      for (int n = 0; n < 4; ++n) {
        acc[m][n] = __builtin_amdgcn_mfma_f32_16x16x32_bf16(ahf[m], blf[n], acc[m][n], 0, 0, 0);
        acc[m][n] = __builtin_amdgcn_mfma_f32_16x16x32_bf16(alf[m], bhf[n], acc[m][n], 0, 0, 0);
        acc[m][n] = __builtin_amdgcn_mfma_f32_16x16x32_bf16(ahf[m], bhf[n], acc[m][n], 0, 0, 0);
      }
  }

  int gcb = w * 64;
  if (w < 2) {
    // cols 0..127 -> hs
#pragma unroll
    for (int m = 0; m < 4; ++m)
#pragma unroll
      for (int i = 0; i < 4; ++i) {
        int row = r0 + m * 16 + rq + i;
        if (row < N) {
#pragma unroll
          for (int n = 0; n < 4; ++n)
            hs[(size_t)row * DOUT + gcb + n * 16 + lr] = f2bf(acc[m][n][i]);
        }
      }
  } else {
    int cb = gcb - 128;
    float bav[4];
#pragma unroll
    for (int n = 0; n < 4; ++n) bav[n] = ba[cb + n * 16 + lr];
#pragma unroll
    for (int m = 0; m < 4; ++m)
#pragma unroll
      for (int i = 0; i < 4; ++i) {
        int row = r0 + m * 16 + rq + i;
        if (row < N) {
#pragma unroll
          for (int n = 0; n < 4; ++n)
            t[(size_t)row * TCOLS + cb + n * 16 + lr] =
                f2bf(fmaxf(acc[m][n][i] + bav[n], 0.f));
        }
      }
  }
}

// ---------------------------------------------------------------- VtZ + colsum, stage 1 (atomic-free)
// Double-buffered LDS pipeline -- stage tile k+1 while computing tile k.
#define STAGE_RED(BUF, TILE)                                                     \
  {                                                                              \
    int r0_ = (TILE) * 32;                                                       \
    for (int i_ = tid; i_ < 768; i_ += 256) {                                    \
      int r_ = i_ / 24, c0_ = (i_ % 24) * 8;                                     \
      int row_ = r0_ + r_;                                                       \
      ushort4 v0_, v1_;                                                          \
      if (row_ < N) {                                                            \
        v0_ = ((const ushort4*)&t[(size_t)row_ * TCOLS + c0_])[0];               \
        v1_ = ((const ushort4*)&t[(size_t)row_ * TCOLS + c0_])[1];               \
      } else {                                                                   \
        v0_ = make_ushort4(0, 0, 0, 0); v1_ = v0_;                               \
      }                                                                          \
      *(ushort4*)&ts[BUF][r_ * 200 + c0_] = v0_;                                 \
      *(ushort4*)&ts[BUF][r_ * 200 + c0_ + 4] = v1_;                             \
    }                                                                            \
  }

__global__ __launch_bounds__(256) void k_red(const ushort_t* __restrict__ t, float* __restrict__ part,
                                             int N) {
  __shared__ ushort_t ts[2][32 * 200];   // 2 x 12.5KB ping-pong
  __shared__ float csh[512];
  int tid = threadIdx.x;
  int lane = tid & 63;
  int w = tid >> 6;            // wave 0..3 -> V-col strip w*16
  int lr = lane & 15;
  int lk = (lane >> 4) * 8;
  int vcol = 64 + w * 16 + lr; // t-col of A-operand (V region)
  int col2 = lane * 2;         // colsum col pair (0..127)

  f32x4 acc[4] = {};
  float cs0 = 0.f, cs1 = 0.f;
  int ntiles = (N + 31) >> 5;
  int cur = 0;

  int tile = blockIdx.x;
  if (tile < ntiles) STAGE_RED(0, tile);
  __syncthreads();
  for (; tile < ntiles; tile += gridDim.x) {
    int nxt = tile + gridDim.x;
    if (nxt < ntiles) STAGE_RED(cur ^ 1, nxt);
    const ushort_t* tb = ts[cur];
    bf16x8 a, b[4];
#pragma unroll
    for (int j = 0; j < 8; ++j)
      ((ushort_t*)&a)[j] = tb[(lk + j) * 200 + vcol];
#pragma unroll
    for (int n = 0; n < 4; ++n)
#pragma unroll
      for (int j = 0; j < 8; ++j)
        ((ushort_t*)&b[n])[j] = tb[(lk + j) * 200 + 128 + n * 16 + lr];
#pragma unroll
    for (int j = 0; j < 8; ++j) {
      ushort2 u = *(const ushort2*)&tb[(w * 8 + j) * 200 + col2];
      cs0 += bf2f(u.x); cs1 += bf2f(u.y);
    }
#pragma unroll
    for (int n = 0; n < 4; ++n)
      acc[n] = __builtin_amdgcn_mfma_f32_16x16x32_bf16(a, b[n], acc[n], 0, 0, 0);
    __syncthreads();
    cur ^= 1;
  }

  float* pb = &part[(size_t)blockIdx.x * PSTR];
  int rq = (lane >> 4) * 4;
#pragma unroll
  for (int n = 0; n < 4; ++n)
#pragma unroll
    for (int i = 0; i < 4; ++i)
      pb[(w * 16 + rq + i) * 64 + n * 16 + lr] = acc[n][i];

  csh[tid] = cs0;
  csh[256 + tid] = cs1;
  __syncthreads();
  if (w == 0) {
    float t0 = csh[lane] + csh[64 + lane] + csh[128 + lane] + csh[192 + lane];
    float t1 = csh[256 + lane] + csh[320 + lane] + csh[384 + lane] + csh[448 + lane];
    pb[4096 + col2] = t0;
    pb[4096 + col2 + 1] = t1;
  }
}

// ---------------------------------------------------------------- stage 2: sum P_RED partials
__global__ __launch_bounds__(256) void k_redsum(const float* __restrict__ part,
                                                float* __restrict__ VtZ, float* __restrict__ colsum) {
  __shared__ float s[256];
  int tid = threadIdx.x;
  int j = blockIdx.x * 64 + (tid & 63);
  int bc = tid >> 6;           // 0..3
  float a = 0.f;
#pragma unroll 4
  for (int b = bc; b < P_RED; b += 4) a += part[(size_t)b * PSTR + j];
  s[tid] = a;
  __syncthreads();
  if (bc == 0) {
    float v = s[tid] + s[tid + 64] + s[tid + 128] + s[tid + 192];
    if (j < 4096) VtZ[j] = v;
    else colsum[j - 4096] = v;
  }
}

// ---------------------------------------------------------------- Weff build, FRAGMENT ORDER.
// D = N/dot(colsumU,colsumV) computed per-block in LDS (k_d folded in).
__global__ __launch_bounds__(256) void k_prep(const float* __restrict__ VtZ,
                                              const float* __restrict__ colsum,
                                              const float* __restrict__ Wr,
                                              ushort_t* __restrict__ weffF, int N) {
  __shared__ float dsh[64];
  __shared__ float Dsh;
  int tid = threadIdx.x;
  if (tid < 64) dsh[tid] = colsum[tid] * colsum[64 + tid];
  __syncthreads();
  if (tid == 0) {
    float p = 0.f;
#pragma unroll 8
    for (int i = 0; i < 64; ++i) p += dsh[i];
    Dsh = (p != 0.f) ? ((float)N / p) : 0.f;
  }
  __syncthreads();
  float Dv = Dsh;

  int g = blockIdx.x * 256 + tid;   // 16 blocks
  int f = g >> 6, l = g & 63;
  int c16 = f >> 3, s = f & 7;
  int c = c16 * 16 + (l & 15);
  int k0 = s * 32 + ((l >> 4) << 3);
#pragma unroll
  for (int j = 0; j < 8; ++j) {
    int k = k0 + j;
    float v;
    if (k < 128 || k >= 192) {
      v = Wr[(size_t)k * DOUT + c];
    } else {
      int kk = k - 128;
      float acc = 0.f;
      for (int q = 0; q < 64; ++q)
        acc += VtZ[kk * 64 + q] * Wr[(size_t)(128 + q) * DOUT + c];
      v = acc * Dv;
    }
    weffF[(size_t)g * 8 + j] = f2bf(v);
  }
}

// ---------------------------------------------------------------- FUSED aggregate + output GEMM.
__global__ __launch_bounds__(256) void k_aggout(const ushort_t* __restrict__ hs,
                                                const int2* __restrict__ csr,
                                                const int* __restrict__ offs,
                                                const float* __restrict__ dinv,
                                                const float* __restrict__ bg,
                                                const ushort_t* __restrict__ t,
                                                const ushort_t* __restrict__ weffF,
                                                const float* __restrict__ br,
                                                float* __restrict__ out, int N) {
  __shared__ ushort_t ys[32 * 264];   // [row][col 0..255], stride 264 (b128-aligned)
  int tid = threadIdx.x;
  int lane = tid & 63;
  int w = tid >> 6;
  int lr = lane & 15;
  int lk = (lane >> 4) * 8;
  int rq = (lane >> 4) * 4;
  int r0 = blockIdx.x * 32;
  int c2 = 2 * lane;

  // phase 0 (issued first, hides under the gather): stage cols 128..255
  for (int i = tid; i < 512; i += 256) {
    int r = i >> 4, c0 = 128 + (i & 15) * 8;
    int row = r0 + r;
    ushort4 v0, v1;
    if (row < N) {
      const ushort_t* src = (c0 < 192) ? &t[(size_t)row * TCOLS + (c0 - 128)]
                                       : &t[(size_t)row * TCOLS + c0];
      v0 = ((const ushort4*)src)[0];
      v1 = ((const ushort4*)src)[1];
    } else {
      v0 = make_ushort4(0, 0, 0, 0); v1 = v0;
    }
    *(ushort4*)&ys[r * 264 + c0] = v0;
    *(ushort4*)&ys[r * 264 + c0 + 4] = v1;
  }

  // phase 1: aggregate 8 nodes per wave -> ys cols 0..127
  float bg0 = bg[c2], bg1 = bg[c2 + 1];
  for (int q = 0; q < 8; ++q) {
    int r = w * 8 + q;
    int node = r0 + r;
    ushort2 o = make_ushort2(0, 0);
    if (node < N) {
      float dn = dinv[node];
      ushort2 u = *(const ushort2*)&hs[(size_t)node * DOUT + c2];
      float a0 = dn * dn * bf2f(u.x);
      float a1 = dn * dn * bf2f(u.y);
      int e = offs[node], e1 = offs[node + 1];
      for (; e + 4 <= e1; e += 4) {
        int2 q0 = csr[e], q1 = csr[e + 1], q2 = csr[e + 2], q3 = csr[e + 3];
        ushort2 r0v = *(const ushort2*)&hs[(size_t)q0.x * DOUT + c2];
        ushort2 r1v = *(const ushort2*)&hs[(size_t)q1.x * DOUT + c2];
        ushort2 r2v = *(const ushort2*)&hs[(size_t)q2.x * DOUT + c2];
        ushort2 r3v = *(const ushort2*)&hs[(size_t)q3.x * DOUT + c2];
        float n0 = __int_as_float(q0.y), n1 = __int_as_float(q1.y);
        float n2 = __int_as_float(q2.y), n3 = __int_as_float(q3.y);
        a0 += n0 * bf2f(r0v.x) + n1 * bf2f(r1v.x) + n2 * bf2f(r2v.x) + n3 * bf2f(r3v.x);
        a1 += n0 * bf2f(r0v.y) + n1 * bf2f(r1v.y) + n2 * bf2f(r2v.y) + n3 * bf2f(r3v.y);
      }
      for (; e < e1; ++e) {
        int2 qe = csr[e];
        ushort2 rv = *(const ushort2*)&hs[(size_t)qe.x * DOUT + c2];
        float n0 = __int_as_float(qe.y);
        a0 += n0 * bf2f(rv.x);
        a1 += n0 * bf2f(rv.y);
      }
      o.x = f2bf(fmaxf(a0 + bg0, 0.f));
      o.y = f2bf(fmaxf(a1 + bg1, 0.f));
    }
    *(ushort2*)&ys[r * 264 + c2] = o;
  }
  __syncthreads();

  // phase 2: out[32x128] = y @ Weff + br
  f32x4 acc[2][2] = {};
#pragma unroll
  for (int s = 0; s < 8; ++s) {
    bf16x8 a[2], b[2];
#pragma unroll
    for (int m = 0; m < 2; ++m)
      a[m] = *(const bf16x8*)&ys[(m * 16 + lr) * 264 + s * 32 + lk];
#pragma unroll
    for (int n = 0; n < 2; ++n) {
      int f = (w * 2 + n) * 8 + s;
      b[n] = *(const bf16x8*)&weffF[((size_t)f * 64 + lane) * 8];
    }
#pragma unroll
    for (int m = 0; m < 2; ++m)
#pragma unroll
      for (int n = 0; n < 2; ++n)
        acc[m][n] = __builtin_amdgcn_mfma_f32_16x16x32_bf16(a[m], b[n], acc[m][n], 0, 0, 0);
  }

  float brv[2];
#pragma unroll
  for (int n = 0; n < 2; ++n) brv[n] = br[w * 32 + n * 16 + lr];
#pragma unroll
  for (int m = 0; m < 2; ++m)
#pragma unroll
    for (int i = 0; i < 4; ++i) {
      int row = r0 + m * 16 + rq + i;
      if (row < N) {
#pragma unroll
        for (int n = 0; n < 2; ++n)
          out[(size_t)row * DOUT + w * 32 + n * 16 + lr] = acc[m][n][i] + brv[n];
      }
    }
}

// ---------------------------------------------------------------- launch
extern "C" void kernel_launch(void* const* d_in, const int* in_sizes, int n_in,
                              void* d_out, int out_size, void* d_ws, size_t ws_size,
                              hipStream_t stream) {
  const float* x  = (const float*)d_in[0];
  const int* ei   = (const int*)d_in[1];
  const float* Wg = (const float*)d_in[2];
  const float* bg = (const float*)d_in[3];
  const float* Wa = (const float*)d_in[4];
  const float* ba = (const float*)d_in[5];
  const float* Wr = (const float*)d_in[6];
  const float* br = (const float*)d_in[7];
  float* out = (float*)d_out;     // fp32 output

  const int N = in_sizes[0] / DIN;
  const int E = in_sizes[1] / 2;

  const int B = (N + 1023) >> 10;       // coarse dst buckets (<=128)
  const int CAP = ((E / (B > 0 ? B : 1)) * 3 / 2 + 255) & ~255;  // 1.5x headroom

  char* p = (char*)d_ws;
  auto alloc = [&](size_t bytes) {
    char* r = p;
    p += (bytes + 255) & ~(size_t)255;
    return r;
  };
  float* colsum = (float*)alloc(128 * 4);
  float* VtZ    = (float*)alloc(4096 * 4);
  int*   bsums  = (int*)alloc(1024);
  int*   boff   = (int*)alloc(1024);
  int*   bcur   = (int*)alloc(1024);
  int*   ocnt   = (int*)alloc(256);
  ushort_t* weffF = (ushort_t*)alloc(128 * 256 * 2);        // bf16 Weff, fragment order
  ushort_t* whF = (ushort_t*)alloc((size_t)24 * 4 * 512 * 2); // weight frags hi (96KB)
  ushort_t* wlF = (ushort_t*)alloc((size_t)24 * 4 * 512 * 2); // weight frags lo
  float* part   = (float*)alloc((size_t)P_RED * PSTR * 4);  // stage-1 partials (8.3 MB)
  int*   degc   = (int*)alloc((size_t)N * 4);
  float* dinv   = (float*)alloc((size_t)N * 4);
  int*   offs   = (int*)alloc((size_t)(N + 1) * 4);
  int2*  csr    = (int2*)alloc((size_t)E * 8);              // (src, norm) per edge
  int2*  buckets= (int2*)alloc((size_t)B * CAP * 8);        // pass-A bins (~19MB)
  int2*  oflow  = (int2*)alloc((size_t)E * 8);              // overflow list (12.8MB)
  ushort_t* hs  = (ushort_t*)alloc((size_t)N * DOUT * 2);   // bf16 x@Wg
  ushort_t* t   = (ushort_t*)alloc((size_t)N * TCOLS * 2);  // bf16 relu(x@Wa+ba)
  (void)ws_size; (void)n_in; (void)out_size;

  const int GN = (N + 255) / 256;
  const int NBLK = (N + 1023) / 1024;   // <= 128 for N <= 131072
  const int GBIN = (E + 4095) / 4096;
  const int NT64 = (N + 63) / 64;       // row tiles for k_gemm1f
  const int NT32 = (N + 31) / 32;       // row tiles for k_aggout

  k_init<<<GN, 256, 0, stream>>>(degc, VtZ, colsum, bcur, ocnt, N);
  k_bin<<<GBIN, 256, 0, stream>>>(ei, bcur, degc, buckets, oflow, ocnt, E, B, CAP);
  k_wprep<<<24, 256, 0, stream>>>(Wg, Wa, whF, wlF);
  k_scan1<<<NBLK, 256, 0, stream>>>(degc, offs, bsums, N);
  k_scan2<<<1, 128, 0, stream>>>(bsums, boff, offs, NBLK, N);
  k_scan3<<<GN, 256, 0, stream>>>(offs, boff, degc, dinv, N);
  k_scatter2<<<B * 4, 256, 0, stream>>>(buckets, bcur, offs, dinv, oflow, ocnt, csr, CAP, N);
  k_gemm1f<<<NT64, 384, 0, stream>>>(x, whF, wlF, ba, hs, t, N);
  k_red<<<P_RED, 256, 0, stream>>>(t, part, N);
  k_redsum<<<PSTR / 64, 256, 0, stream>>>(part, VtZ, colsum);
  k_prep<<<16, 256, 0, stream>>>(VtZ, colsum, Wr, weffF, N);
  k_aggout<<<NT32, 256, 0, stream>>>(hs, csr, offs, dinv, bg, t, weffF, br, out, N);
}

// Round 14
// 418.466 us; speedup vs baseline: 1.0149x; 1.0149x over previous
//
#include <hip/hip_runtime.h>

// GCN + low-rank global attention (LRGA), N=100k, E=1.6M, D=128, K=64.
// R1: k_out -> bf16 MFMA with folded Weff.
// R2: k_gemm1 -> split-bf16 (hi/lo) MFMA 3-pass.
// R3: k_red -> atomic-free two-stage MFMA reduction.
// R4: FAILED (fused split in k-loop / weight hoist). R5: reg dbuf = null.
// R6: scatter XCD-shard = null. R7: fragment-order gemm1 layouts. WIN.
// R8: HW lesson: sparse 8B stores cost a full HBM line; only dense stores avoid it.
// R9: scatter -> LDS counting sort + dense flush. WIN.
// R10: k_red/k_out coalescing = ~null. R11: k_deg fold + aggn/out fuse. WIN.
// R12: k_red dbuf pipeline; k_d/k_fixup folds. WIN (418.9us -- session best).
// R13: split+gemm fusion REGRESSED (425us): streaming round-trips at 5-6 TB/s are
//      cheaper than shortening the per-block pipeline. REVERTED to R12 config.
#define DIN   128
#define DOUT  128
#define KR    64
#define TCOLS 256   // 4*K
#define WCOLS 384   // DOUT + TCOLS
#define P_RED 512   // stage-1 partial blocks
#define PSTR  4224  // 4096 VtZ + 128 colsum
#define STCAP 6144  // pass-B LDS staging (edges per 256-node quarter, 1.5x mean)

typedef unsigned short ushort_t;
typedef __attribute__((ext_vector_type(8))) short bf16x8;
typedef __attribute__((ext_vector_type(4))) float f32x4;

__device__ __forceinline__ float bf2f(unsigned short u) {
  return __uint_as_float(((unsigned int)u) << 16);
}
__device__ __forceinline__ unsigned short f2bf(float f) {
  unsigned int b = __float_as_uint(f);
  b = b + 0x7FFFu + ((b >> 16) & 1u);
  return (unsigned short)(b >> 16);
}

// ---------------------------------------------------------------- init
__global__ __launch_bounds__(256) void k_init(int* __restrict__ degc, float* __restrict__ VtZ,
                                              float* __restrict__ colsum, int* __restrict__ bcur,
                                              int* __restrict__ ocnt, int N) {
  int i = blockIdx.x * 256 + threadIdx.x;
  if (i < N) degc[i] = 1;            // self-loop gives deg >= 1
  if (i < 4096) VtZ[i] = 0.f;
  if (i < 128) colsum[i] = 0.f;
  if (i < 128) bcur[i] = 0;
  if (i == 0) ocnt[0] = 0;
}

// ---------------------------------------------------------------- x -> bf16 hi/lo split, FRAGMENT ORDER.
__global__ __launch_bounds__(256) void k_split(const float* __restrict__ x,
                                               ushort_t* __restrict__ xhF, ushort_t* __restrict__ xloF,
                                               int N, int total_slots) {
  int gid = blockIdx.x * 256 + threadIdx.x;
  int stride = gridDim.x * 256;
  for (; gid < total_slots; gid += stride) {
    int f = gid >> 6, l = gid & 63;
    int r16 = f >> 2, s = f & 3;
    int row = r16 * 16 + (l & 15);
    int k = s * 32 + ((l >> 4) << 3);
    ushort4 h0, h1, l0, l1;
    if (row < N) {
      float4 a = *(const float4*)&x[(size_t)row * DIN + k];
      float4 b = *(const float4*)&x[(size_t)row * DIN + k + 4];
      h0.x = f2bf(a.x); h0.y = f2bf(a.y); h0.z = f2bf(a.z); h0.w = f2bf(a.w);
      h1.x = f2bf(b.x); h1.y = f2bf(b.y); h1.z = f2bf(b.z); h1.w = f2bf(b.w);
      l0.x = f2bf(a.x - bf2f(h0.x)); l0.y = f2bf(a.y - bf2f(h0.y));
      l0.z = f2bf(a.z - bf2f(h0.z)); l0.w = f2bf(a.w - bf2f(h0.w));
      l1.x = f2bf(b.x - bf2f(h1.x)); l1.y = f2bf(b.y - bf2f(h1.y));
      l1.z = f2bf(b.z - bf2f(h1.z)); l1.w = f2bf(b.w - bf2f(h1.w));
    } else {
      h0 = make_ushort4(0, 0, 0, 0); h1 = h0; l0 = h0; l1 = h0;
    }
    ((ushort4*)xhF)[gid * 2] = h0;
    ((ushort4*)xhF)[gid * 2 + 1] = h1;
    ((ushort4*)xloF)[gid * 2] = l0;
    ((ushort4*)xloF)[gid * 2 + 1] = l1;
  }
}

// ---------------------------------------------------------------- weights -> bf16 hi/lo, FRAGMENT ORDER.
__global__ __launch_bounds__(256) void k_wprep(const float* __restrict__ Wg, const float* __restrict__ Wa,
                                               ushort_t* __restrict__ whF, ushort_t* __restrict__ wlF) {
  int g = blockIdx.x * 256 + threadIdx.x;
  int f = g >> 6, l = g & 63;
  int c16 = f >> 2, s = f & 3;
  int col = c16 * 16 + (l & 15);
  int k = s * 32 + ((l >> 4) << 3);
#pragma unroll
  for (int j = 0; j < 8; ++j) {
    float v = (col < DOUT) ? Wg[(size_t)(k + j) * DOUT + col]
                           : Wa[(size_t)(k + j) * TCOLS + (col - DOUT)];
    ushort_t h = f2bf(v);
    whF[(size_t)g * 8 + j] = h;
    wlF[(size_t)g * 8 + j] = f2bf(v - bf2f(h));
  }
}

// ---------------------------------------------------------------- hierarchical scan, stage 1
__global__ __launch_bounds__(256) void k_scan1(const int* __restrict__ degc, int* __restrict__ offs,
                                               int* __restrict__ bsums, int N) {
  __shared__ int s[256];
  int tid = threadIdx.x;
  int base = blockIdx.x * 1024 + tid * 4;
  int c[4], e[4];
#pragma unroll
  for (int q = 0; q < 4; ++q) c[q] = (base + q < N) ? (degc[base + q] - 1) : 0;
  e[0] = 0; e[1] = c[0]; e[2] = e[1] + c[1]; e[3] = e[2] + c[2];
  int tsum = e[3] + c[3];
  s[tid] = tsum; __syncthreads();
  for (int off = 1; off < 256; off <<= 1) {
    int v = (tid >= off) ? s[tid - off] : 0;
    __syncthreads();
    s[tid] += v;
    __syncthreads();
  }
  int tb = s[tid] - tsum;
#pragma unroll
  for (int q = 0; q < 4; ++q) if (base + q < N) offs[base + q] = tb + e[q];
  if (tid == 255) bsums[blockIdx.x] = s[255];
}

// stage 2: exclusive scan of block sums (NBLK <= 128)
__global__ __launch_bounds__(128) void k_scan2(const int* __restrict__ bsums, int* __restrict__ boff,
                                               int* __restrict__ offs, int NBLK, int N) {
  __shared__ int s[128];
  int tid = threadIdx.x;
  int v = (tid < NBLK) ? bsums[tid] : 0;
  s[tid] = v; __syncthreads();
  for (int off = 1; off < 128; off <<= 1) {
    int u = (tid >= off) ? s[tid - off] : 0;
    __syncthreads();
    s[tid] += u;
    __syncthreads();
  }
  boff[tid] = s[tid] - v;
  if (tid == 127) offs[N] = s[127];   // total = E
}

// stage 3: add block offsets; dinv = rsqrt(deg)
__global__ __launch_bounds__(256) void k_scan3(int* __restrict__ offs, const int* __restrict__ boff,
                                               const int* __restrict__ degc, float* __restrict__ dinv,
                                               int N) {
  int i = blockIdx.x * 256 + threadIdx.x;
  if (i < N) {
    offs[i] += boff[i >> 10];
    dinv[i] = rsqrtf((float)degc[i]);
  }
}

// ---------------------------------------------------------------- pass A: bin edges by dst range (1024-node bins).
// Also accumulates degc (k_deg folded in).
__global__ __launch_bounds__(256) void k_bin(const int* __restrict__ ei, int* __restrict__ bcur,
                                             int* __restrict__ degc,
                                             int2* __restrict__ buckets,
                                             int2* __restrict__ oflow, int* __restrict__ ocnt,
                                             int E, int B, int CAP) {
  __shared__ int hist[128], pref[128], place[128], gbase[128];
  __shared__ int2 st[4096];
  int tid = threadIdx.x;
  int e0 = blockIdx.x * 4096;
  int nE = min(4096, E - e0);
  if (nE <= 0) return;

  if (tid < 128) { hist[tid] = 0; place[tid] = 0; }
  __syncthreads();

  int src[16], dst[16];
#pragma unroll
  for (int q = 0; q < 16; ++q) {
    int idx = tid + q * 256;
    if (idx < nE) {
      src[q] = ei[e0 + idx];
      dst[q] = ei[E + e0 + idx];
      atomicAdd(&hist[dst[q] >> 10], 1);
      atomicAdd(&degc[dst[q]], 1);          // folded k_deg
    }
  }
  __syncthreads();

  if (tid < 128) pref[tid] = hist[tid];
  __syncthreads();
  for (int off = 1; off < 128; off <<= 1) {
    int v = (tid < 128 && tid >= off) ? pref[tid - off] : 0;
    __syncthreads();
    if (tid < 128) pref[tid] += v;
    __syncthreads();
  }
  if (tid < 128) pref[tid] -= hist[tid];
  if (tid < B && hist[tid] > 0) gbase[tid] = atomicAdd(&bcur[tid], hist[tid]);
  __syncthreads();

#pragma unroll
  for (int q = 0; q < 16; ++q) {
    int idx = tid + q * 256;
    if (idx < nE) {
      int b = dst[q] >> 10;
      int p = pref[b] + atomicAdd(&place[b], 1);
      st[p] = make_int2(src[q], dst[q]);
    }
  }
  __syncthreads();

  for (int i = tid; i < nE; i += 256) {
    int2 q = st[i];
    int b = q.y >> 10;
    int gp = gbase[b] + (i - pref[b]);
    if (gp < CAP) {
      buckets[(size_t)b * CAP + gp] = q;
    } else {
      int oi = atomicAdd(ocnt, 1);
      oflow[oi] = q;
    }
  }
}

// ---------------------------------------------------------------- pass B: LDS counting sort, dense flush.
// Pass-A overflow handled in-block after the flush (k_fixup folded in).
__global__ __launch_bounds__(256) void k_scatter2(const int2* __restrict__ buckets,
                                                  const int* __restrict__ bcur,
                                                  const int* __restrict__ offs,
                                                  const float* __restrict__ dinv,
                                                  const int2* __restrict__ oflow,
                                                  const int* __restrict__ ocnt,
                                                  int2* __restrict__ csr, int CAP, int N) {
  __shared__ int lcur[256];
  __shared__ int2 st[STCAP];
  int cb = blockIdx.x >> 2;
  int lo = cb * 1024 + (blockIdx.x & 3) * 256;
  if (lo >= N) return;
  int tid = threadIdx.x;
  int nnode = min(256, N - lo);
  int base = offs[lo];
  int nb = offs[lo + nnode] - base;     // true edge count for this quarter
  if (tid < nnode) lcur[tid] = offs[lo + tid];   // absolute positions
  __syncthreads();
  int avail = min(bcur[cb], CAP);
  const int2* sp = &buckets[(size_t)cb * CAP];
  bool staged = (nb <= STCAP);
  int quarter = lo >> 8;
  for (int i = tid; i < avail; i += 256) {
    int2 q = sp[i];
    if ((q.y >> 8) != quarter) continue;
    int p = atomicAdd(&lcur[q.y - lo], 1);
    int2 c;
    c.x = q.x;
    c.y = __float_as_int(dinv[q.x] * dinv[q.y]);
    if (staged) st[p - base] = c;
    else        csr[p] = c;
  }
  __syncthreads();
  if (staged) {
    for (int i = tid; i < nb; i += 256) csr[base + i] = st[i];  // DENSE flush
  }
  __syncthreads();
  // folded fixup: drain pass-A overflow edges belonging to this quarter
  int n = ocnt[0];
  for (int i = tid; i < n; i += 256) {
    int2 q = oflow[i];
    if ((q.y >> 8) != quarter) continue;
    int p = atomicAdd(&lcur[q.y - lo], 1);
    int2 c;
    c.x = q.x;
    c.y = __float_as_int(dinv[q.x] * dinv[q.y]);
    csr[p] = c;
  }
}

// ---------------------------------------------------------------- fused GEMM via MFMA (split bf16, 3-pass)
#define LOADK(S, AH, AL, BH, BL)                                              \
  {                                                                           \
    _Pragma("unroll") for (int m_ = 0; m_ < 4; ++m_) {                        \
      size_t fo_ = (((size_t)(r16b + m_) * 4 + (S)) * 64 + lane) * 8;         \
      AH[m_] = *(const bf16x8*)&xhF[fo_];                                     \
      AL[m_] = *(const bf16x8*)&xloF[fo_];                                    \
    }                                                                         \
    _Pragma("unroll") for (int n_ = 0; n_ < 4; ++n_) {                        \
      size_t fo_ = (((size_t)(c16b + n_) * 4 + (S)) * 64 + lane) * 8;         \
      BH[n_] = *(const bf16x8*)&whF[fo_];                                     \
      BL[n_] = *(const bf16x8*)&wlF[fo_];                                     \
    }                                                                         \
  }

__global__ __launch_bounds__(256) void k_gemm1_mfma(const ushort_t* __restrict__ xhF,
                                                    const ushort_t* __restrict__ xloF,
                                                    const ushort_t* __restrict__ whF,
                                                    const ushort_t* __restrict__ wlF,
                                                    const float* __restrict__ ba,
                                                    ushort_t* __restrict__ hs, ushort_t* __restrict__ t,
                                                    int N, int ntiles) {
  int bid = blockIdx.x;
  int g = bid / 24;
  int rem = bid - g * 24;
  int colblk = rem >> 3;              // 0..2
  int ytile = g * 8 + (rem & 7);
  if (ytile >= ntiles) return;

  int tid = threadIdx.x;
  int lane = tid & 63;
  int wave = tid >> 6;
  int wr = wave >> 1, wc = wave & 1;
  int rowbase = ytile * 128 + wr * 64;
  int gcb = colblk * 128 + wc * 64;        // global col base of this wave (0..383)
  int r16b = ytile * 8 + wr * 4;           // A row-group base (16-row units)
  int c16b = colblk * 8 + wc * 4;          // B col-group base (16-col units)
  int lr = lane & 15;
  int rq = (lane >> 4) * 4;

  f32x4 acc[4][4] = {};
  bf16x8 ah[2][4], al[2][4], bh[2][4], bl[2][4];

  LOADK(0, ah[0], al[0], bh[0], bl[0]);
#pragma unroll
  for (int s = 0; s < 4; ++s) {
    int cur = s & 1, nxt = cur ^ 1;
    if (s < 3) LOADK(s + 1, ah[nxt], al[nxt], bh[nxt], bl[nxt]);
#pragma unroll
    for (int m = 0; m < 4; ++m)
#pragma unroll
      for (int n = 0; n < 4; ++n) {
        acc[m][n] = __builtin_amdgcn_mfma_f32_16x16x32_bf16(ah[cur][m], bl[cur][n], acc[m][n], 0, 0, 0);
        acc[m][n] = __builtin_amdgcn_mfma_f32_16x16x32_bf16(al[cur][m], bh[cur][n], acc[m][n], 0, 0, 0);
        acc[m][n] = __builtin_amdgcn_mfma_f32_16x16x32_bf16(ah[cur][m], bh[cur][n], acc[m][n], 0, 0, 0);
      }
  }

  if (colblk == 0) {
#pragma unroll
    for (int m = 0; m < 4; ++m)
#pragma unroll
      for (int i = 0; i < 4; ++i) {
        int row = rowbase + m * 16 + rq + i;
        if (row < N) {
#pragma unroll
          for (int n = 0; n < 4; ++n)
            hs[(size_t)row * DOUT + gcb + n * 16 + lr] = f2bf(acc[m][n][i]);
        }
      }
  } else {
    float bav[4];
#pragma unroll
    for (int n = 0; n < 4; ++n) bav[n] = ba[gcb - DOUT + n * 16 + lr];
#pragma unroll
    for (int m = 0; m < 4; ++m)
#pragma unroll
      for (int i = 0; i < 4; ++i) {
        int row = rowbase + m * 16 + rq + i;
        if (row < N) {
#pragma unroll
          for (int n = 0; n < 4; ++n)
            t[(size_t)row * TCOLS + gcb - DOUT + n * 16 + lr] =
                f2bf(fmaxf(acc[m][n][i] + bav[n], 0.f));
        }
      }
  }
}

// ---------------------------------------------------------------- VtZ + colsum, stage 1 (atomic-free)
// Double-buffered LDS pipeline -- stage tile k+1 while computing tile k.
#define STAGE_RED(BUF, TILE)                                                     \
  {                                                                              \
    int r0_ = (TILE) * 32;                                                       \
    for (int i_ = tid; i_ < 768; i_ += 256) {                                    \
      int r_ = i_ / 24, c0_ = (i_ % 24) * 8;                                     \
      int row_ = r0_ + r_;                                                       \
      ushort4 v0_, v1_;                                                          \
      if (row_ < N) {                                                            \
        v0_ = ((const ushort4*)&t[(size_t)row_ * TCOLS + c0_])[0];               \
        v1_ = ((const ushort4*)&t[(size_t)row_ * TCOLS + c0_])[1];               \
      } else {                                                                   \
        v0_ = make_ushort4(0, 0, 0, 0); v1_ = v0_;                               \
      }                                                                          \
      *(ushort4*)&ts[BUF][r_ * 200 + c0_] = v0_;                                 \
      *(ushort4*)&ts[BUF][r_ * 200 + c0_ + 4] = v1_;                             \
    }                                                                            \
  }

__global__ __launch_bounds__(256) void k_red(const ushort_t* __restrict__ t, float* __restrict__ part,
                                             int N) {
  __shared__ ushort_t ts[2][32 * 200];   // 2 x 12.5KB ping-pong
  __shared__ float csh[512];
  int tid = threadIdx.x;
  int lane = tid & 63;
  int w = tid >> 6;            // wave 0..3 -> V-col strip w*16
  int lr = lane & 15;
  int lk = (lane >> 4) * 8;
  int vcol = 64 + w * 16 + lr; // t-col of A-operand (V region)
  int col2 = lane * 2;         // colsum col pair (0..127)

  f32x4 acc[4] = {};
  float cs0 = 0.f, cs1 = 0.f;
  int ntiles = (N + 31) >> 5;
  int cur = 0;

  int tile = blockIdx.x;
  if (tile < ntiles) STAGE_RED(0, tile);
  __syncthreads();
  for (; tile < ntiles; tile += gridDim.x) {
    int nxt = tile + gridDim.x;
    if (nxt < ntiles) STAGE_RED(cur ^ 1, nxt);
    const ushort_t* tb = ts[cur];
    bf16x8 a, b[4];
#pragma unroll
    for (int j = 0; j < 8; ++j)
      ((ushort_t*)&a)[j] = tb[(lk + j) * 200 + vcol];
#pragma unroll
    for (int n = 0; n < 4; ++n)
#pragma unroll
      for (int j = 0; j < 8; ++j)
        ((ushort_t*)&b[n])[j] = tb[(lk + j) * 200 + 128 + n * 16 + lr];
#pragma unroll
    for (int j = 0; j < 8; ++j) {
      ushort2 u = *(const ushort2*)&tb[(w * 8 + j) * 200 + col2];
      cs0 += bf2f(u.x); cs1 += bf2f(u.y);
    }
#pragma unroll
    for (int n = 0; n < 4; ++n)
      acc[n] = __builtin_amdgcn_mfma_f32_16x16x32_bf16(a, b[n], acc[n], 0, 0, 0);
    __syncthreads();
    cur ^= 1;
  }

  float* pb = &part[(size_t)blockIdx.x * PSTR];
  int rq = (lane >> 4) * 4;
#pragma unroll
  for (int n = 0; n < 4; ++n)
#pragma unroll
    for (int i = 0; i < 4; ++i)
      pb[(w * 16 + rq + i) * 64 + n * 16 + lr] = acc[n][i];

  csh[tid] = cs0;
  csh[256 + tid] = cs1;
  __syncthreads();
  if (w == 0) {
    float t0 = csh[lane] + csh[64 + lane] + csh[128 + lane] + csh[192 + lane];
    float t1 = csh[256 + lane] + csh[320 + lane] + csh[384 + lane] + csh[448 + lane];
    pb[4096 + col2] = t0;
    pb[4096 + col2 + 1] = t1;
  }
}

// ---------------------------------------------------------------- stage 2: sum P_RED partials
__global__ __launch_bounds__(256) void k_redsum(const float* __restrict__ part,
                                                float* __restrict__ VtZ, float* __restrict__ colsum) {
  __shared__ float s[256];
  int tid = threadIdx.x;
  int j = blockIdx.x * 64 + (tid & 63);
  int bc = tid >> 6;           // 0..3
  float a = 0.f;
#pragma unroll 4
  for (int b = bc; b < P_RED; b += 4) a += part[(size_t)b * PSTR + j];
  s[tid] = a;
  __syncthreads();
  if (bc == 0) {
    float v = s[tid] + s[tid + 64] + s[tid + 128] + s[tid + 192];
    if (j < 4096) VtZ[j] = v;
    else colsum[j - 4096] = v;
  }
}

// ---------------------------------------------------------------- Weff build, FRAGMENT ORDER.
// D = N/dot(colsumU,colsumV) computed per-block in LDS (k_d folded in).
__global__ __launch_bounds__(256) void k_prep(const float* __restrict__ VtZ,
                                              const float* __restrict__ colsum,
                                              const float* __restrict__ Wr,
                                              ushort_t* __restrict__ weffF, int N) {
  __shared__ float dsh[64];
  __shared__ float Dsh;
  int tid = threadIdx.x;
  if (tid < 64) dsh[tid] = colsum[tid] * colsum[64 + tid];
  __syncthreads();
  if (tid == 0) {
    float p = 0.f;
#pragma unroll 8
    for (int i = 0; i < 64; ++i) p += dsh[i];
    Dsh = (p != 0.f) ? ((float)N / p) : 0.f;
  }
  __syncthreads();
  float Dv = Dsh;

  int g = blockIdx.x * 256 + tid;   // 16 blocks
  int f = g >> 6, l = g & 63;
  int c16 = f >> 3, s = f & 7;
  int c = c16 * 16 + (l & 15);
  int k0 = s * 32 + ((l >> 4) << 3);
#pragma unroll
  for (int j = 0; j < 8; ++j) {
    int k = k0 + j;
    float v;
    if (k < 128 || k >= 192) {
      v = Wr[(size_t)k * DOUT + c];
    } else {
      int kk = k - 128;
      float acc = 0.f;
      for (int q = 0; q < 64; ++q)
        acc += VtZ[kk * 64 + q] * Wr[(size_t)(128 + q) * DOUT + c];
      v = acc * Dv;
    }
    weffF[(size_t)g * 8 + j] = f2bf(v);
  }
}

// ---------------------------------------------------------------- FUSED aggregate + output GEMM.
// t-col staging issued BEFORE the gather so its loads hide under it.
__global__ __launch_bounds__(256) void k_aggout(const ushort_t* __restrict__ hs,
                                                const int2* __restrict__ csr,
                                                const int* __restrict__ offs,
                                                const float* __restrict__ dinv,
                                                const float* __restrict__ bg,
                                                const ushort_t* __restrict__ t,
                                                const ushort_t* __restrict__ weffF,
                                                const float* __restrict__ br,
                                                float* __restrict__ out, int N) {
  __shared__ ushort_t ys[32 * 264];   // [row][col 0..255], stride 264 (b128-aligned)
  int tid = threadIdx.x;
  int lane = tid & 63;
  int w = tid >> 6;
  int lr = lane & 15;
  int lk = (lane >> 4) * 8;
  int rq = (lane >> 4) * 4;
  int r0 = blockIdx.x * 32;
  int c2 = 2 * lane;

  // phase 0 (issued first, hides under the gather): stage cols 128..255
  for (int i = tid; i < 512; i += 256) {
    int r = i >> 4, c0 = 128 + (i & 15) * 8;
    int row = r0 + r;
    ushort4 v0, v1;
    if (row < N) {
      const ushort_t* src = (c0 < 192) ? &t[(size_t)row * TCOLS + (c0 - 128)]
                                       : &t[(size_t)row * TCOLS + c0];
      v0 = ((const ushort4*)src)[0];
      v1 = ((const ushort4*)src)[1];
    } else {
      v0 = make_ushort4(0, 0, 0, 0); v1 = v0;
    }
    *(ushort4*)&ys[r * 264 + c0] = v0;
    *(ushort4*)&ys[r * 264 + c0 + 4] = v1;
  }

  // phase 1: aggregate 8 nodes per wave -> ys cols 0..127
  float bg0 = bg[c2], bg1 = bg[c2 + 1];
  for (int q = 0; q < 8; ++q) {
    int r = w * 8 + q;
    int node = r0 + r;
    ushort2 o = make_ushort2(0, 0);
    if (node < N) {
      float dn = dinv[node];
      ushort2 u = *(const ushort2*)&hs[(size_t)node * DOUT + c2];
      float a0 = dn * dn * bf2f(u.x);
      float a1 = dn * dn * bf2f(u.y);
      int e = offs[node], e1 = offs[node + 1];
      for (; e + 4 <= e1; e += 4) {
        int2 q0 = csr[e], q1 = csr[e + 1], q2 = csr[e + 2], q3 = csr[e + 3];
        ushort2 r0v = *(const ushort2*)&hs[(size_t)q0.x * DOUT + c2];
        ushort2 r1v = *(const ushort2*)&hs[(size_t)q1.x * DOUT + c2];
        ushort2 r2v = *(const ushort2*)&hs[(size_t)q2.x * DOUT + c2];
        ushort2 r3v = *(const ushort2*)&hs[(size_t)q3.x * DOUT + c2];
        float n0 = __int_as_float(q0.y), n1 = __int_as_float(q1.y);
        float n2 = __int_as_float(q2.y), n3 = __int_as_float(q3.y);
        a0 += n0 * bf2f(r0v.x) + n1 * bf2f(r1v.x) + n2 * bf2f(r2v.x) + n3 * bf2f(r3v.x);
        a1 += n0 * bf2f(r0v.y) + n1 * bf2f(r1v.y) + n2 * bf2f(r2v.y) + n3 * bf2f(r3v.y);
      }
      for (; e < e1; ++e) {
        int2 qe = csr[e];
        ushort2 rv = *(const ushort2*)&hs[(size_t)qe.x * DOUT + c2];
        float n0 = __int_as_float(qe.y);
        a0 += n0 * bf2f(rv.x);
        a1 += n0 * bf2f(rv.y);
      }
      o.x = f2bf(fmaxf(a0 + bg0, 0.f));
      o.y = f2bf(fmaxf(a1 + bg1, 0.f));
    }
    *(ushort2*)&ys[r * 264 + c2] = o;
  }
  __syncthreads();

  // phase 2: out[32x128] = y @ Weff + br
  f32x4 acc[2][2] = {};
#pragma unroll
  for (int s = 0; s < 8; ++s) {
    bf16x8 a[2], b[2];
#pragma unroll
    for (int m = 0; m < 2; ++m)
      a[m] = *(const bf16x8*)&ys[(m * 16 + lr) * 264 + s * 32 + lk];
#pragma unroll
    for (int n = 0; n < 2; ++n) {
      int f = (w * 2 + n) * 8 + s;
      b[n] = *(const bf16x8*)&weffF[((size_t)f * 64 + lane) * 8];
    }
#pragma unroll
    for (int m = 0; m < 2; ++m)
#pragma unroll
      for (int n = 0; n < 2; ++n)
        acc[m][n] = __builtin_amdgcn_mfma_f32_16x16x32_bf16(a[m], b[n], acc[m][n], 0, 0, 0);
  }

  float brv[2];
#pragma unroll
  for (int n = 0; n < 2; ++n) brv[n] = br[w * 32 + n * 16 + lr];
#pragma unroll
  for (int m = 0; m < 2; ++m)
#pragma unroll
    for (int i = 0; i < 4; ++i) {
      int row = r0 + m * 16 + rq + i;
      if (row < N) {
#pragma unroll
        for (int n = 0; n < 2; ++n)
          out[(size_t)row * DOUT + w * 32 + n * 16 + lr] = acc[m][n][i] + brv[n];
      }
    }
}

// ---------------------------------------------------------------- launch
extern "C" void kernel_launch(void* const* d_in, const int* in_sizes, int n_in,
                              void* d_out, int out_size, void* d_ws, size_t ws_size,
                              hipStream_t stream) {
  const float* x  = (const float*)d_in[0];
  const int* ei   = (const int*)d_in[1];
  const float* Wg = (const float*)d_in[2];
  const float* bg = (const float*)d_in[3];
  const float* Wa = (const float*)d_in[4];
  const float* ba = (const float*)d_in[5];
  const float* Wr = (const float*)d_in[6];
  const float* br = (const float*)d_in[7];
  float* out = (float*)d_out;     // fp32 output

  const int N = in_sizes[0] / DIN;
  const int E = in_sizes[1] / 2;

  const int NT128 = (N + 127) / 128;    // row tiles for gemm1
  const int N16P = NT128 * 8;           // padded 16-row groups
  const int NFRAG_A = N16P * 4;         // A fragments (1KB each)
  const int B = (N + 1023) >> 10;       // coarse dst buckets (<=128)
  const int CAP = ((E / (B > 0 ? B : 1)) * 3 / 2 + 255) & ~255;  // 1.5x headroom

  char* p = (char*)d_ws;
  auto alloc = [&](size_t bytes) {
    char* r = p;
    p += (bytes + 255) & ~(size_t)255;
    return r;
  };
  float* colsum = (float*)alloc(128 * 4);
  float* VtZ    = (float*)alloc(4096 * 4);
  int*   bsums  = (int*)alloc(1024);
  int*   boff   = (int*)alloc(1024);
  int*   bcur   = (int*)alloc(1024);
  int*   ocnt   = (int*)alloc(256);
  ushort_t* weffF = (ushort_t*)alloc(128 * 256 * 2);        // bf16 Weff, fragment order
  ushort_t* whF = (ushort_t*)alloc((size_t)24 * 4 * 512 * 2); // weight frags hi (96KB)
  ushort_t* wlF = (ushort_t*)alloc((size_t)24 * 4 * 512 * 2); // weight frags lo
  float* part   = (float*)alloc((size_t)P_RED * PSTR * 4);  // stage-1 partials (8.3 MB)
  int*   degc   = (int*)alloc((size_t)N * 4);
  float* dinv   = (float*)alloc((size_t)N * 4);
  int*   offs   = (int*)alloc((size_t)(N + 1) * 4);
  int2*  csr    = (int2*)alloc((size_t)E * 8);              // (src, norm) per edge
  int2*  buckets= (int2*)alloc((size_t)B * CAP * 8);        // pass-A bins (~19MB)
  int2*  oflow  = (int2*)alloc((size_t)E * 8);              // overflow list (12.8MB)
  ushort_t* xhF = (ushort_t*)alloc((size_t)NFRAG_A * 512 * 2); // x frags hi (~25.6MB)
  ushort_t* xloF= (ushort_t*)alloc((size_t)NFRAG_A * 512 * 2); // x frags lo
  ushort_t* hs  = (ushort_t*)alloc((size_t)N * DOUT * 2);   // bf16 x@Wg
  ushort_t* t   = (ushort_t*)alloc((size_t)N * TCOLS * 2);  // bf16 relu(x@Wa+ba)
  (void)ws_size; (void)n_in; (void)out_size;

  const int GN = (N + 255) / 256;
  const int NBLK = (N + 1023) / 1024;   // <= 128 for N <= 131072
  const int G1 = ((NT128 + 7) / 8) * 24;  // swizzled 1-D grid (3 colblks x 8 tiles/group)
  const int GBIN = (E + 4095) / 4096;
  const int NT32 = (N + 31) / 32;       // row tiles for k_aggout

  k_init<<<GN, 256, 0, stream>>>(degc, VtZ, colsum, bcur, ocnt, N);
  k_bin<<<GBIN, 256, 0, stream>>>(ei, bcur, degc, buckets, oflow, ocnt, E, B, CAP);
  k_split<<<2048, 256, 0, stream>>>(x, xhF, xloF, N, NFRAG_A * 64);
  k_wprep<<<24, 256, 0, stream>>>(Wg, Wa, whF, wlF);
  k_scan1<<<NBLK, 256, 0, stream>>>(degc, offs, bsums, N);
  k_scan2<<<1, 128, 0, stream>>>(bsums, boff, offs, NBLK, N);
  k_scan3<<<GN, 256, 0, stream>>>(offs, boff, degc, dinv, N);
  k_scatter2<<<B * 4, 256, 0, stream>>>(buckets, bcur, offs, dinv, oflow, ocnt, csr, CAP, N);
  k_gemm1_mfma<<<G1, 256, 0, stream>>>(xhF, xloF, whF, wlF, ba, hs, t, N, NT128);
  k_red<<<P_RED, 256, 0, stream>>>(t, part, N);
  k_redsum<<<PSTR / 64, 256, 0, stream>>>(part, VtZ, colsum);
  k_prep<<<16, 256, 0, stream>>>(VtZ, colsum, Wr, weffF, N);
  k_aggout<<<NT32, 256, 0, stream>>>(hs, csr, offs, dinv, bg, t, weffF, br, out, N);
}